// Round 8
// baseline (228.695 us; speedup 1.0000x reference)
//
#include <hip/hip_runtime.h>

typedef unsigned short u16;
typedef unsigned int   u32;

#define HW 4096
#define NC 128

typedef __bf16 bf16x8 __attribute__((ext_vector_type(8)));
typedef float  f32x16 __attribute__((ext_vector_type(16)));

__device__ __forceinline__ bf16x8 as_bf8(uint4 u){
    union { uint4 u; bf16x8 b; } c; c.u = u; return c.b;
}
__device__ __forceinline__ u32 pack2(float a, float b){
    return ((__float_as_uint(a) + 0x8000u) >> 16) | ((__float_as_uint(b) + 0x8000u) & 0xffff0000u);
}
__device__ __forceinline__ float bf_lo(u32 u){ return __uint_as_float(u << 16); }
__device__ __forceinline__ float bf_hi(u32 u){ return __uint_as_float(u & 0xffff0000u); }

// 2^x via the HW transcendental unit (avoid glibc __exp2f macro collision)
__device__ __forceinline__ float exp2_hw(float x){ return __builtin_amdgcn_exp2f(x); }

// v_permlane32_swap_b32: 2x2 transpose of 32-lane halves between two VGPRs.
__device__ __forceinline__ void plswap(u32 &a, u32 &b){
    asm("v_permlane32_swap_b32 %0, %1" : "+v"(a), "+v"(b));
}
// proper-RNE pack of two f32 into packed bf16x2 (lo=a, hi=b), 1 instr
__device__ __forceinline__ u32 cvtpk(float a, float b){
    u32 r; asm("v_cvt_pk_bf16_f32 %0, %1, %2" : "=v"(r) : "v"(a), "v"(b)); return r;
}

// ---------------- K1: fused GroupNorm partial sums + weight prep ----------------
__global__ __launch_bounds__(256) void gnw_kernel(const float* __restrict__ x,
                                                  float* __restrict__ stats,
                                                  const float* __restrict__ qkv_w,
                                                  const float* __restrict__ proj_w,
                                                  uint4* __restrict__ Wf,
                                                  uint4* __restrict__ Pf){
    if (blockIdx.x < 256){
        int bg = blockIdx.x >> 3, part = blockIdx.x & 7;
        const float4* p = (const float4*)(x + (size_t)bg * 65536 + part * 8192);
        float s = 0.f, ss = 0.f;
        #pragma unroll
        for (int i = 0; i < 8; i++){
            float4 u = p[threadIdx.x + i*256];
            s  += u.x + u.y + u.z + u.w;
            ss += u.x*u.x + u.y*u.y + u.z*u.z + u.w*u.w;
        }
        #pragma unroll
        for (int off = 32; off > 0; off >>= 1){
            s  += __shfl_xor(s,  off);
            ss += __shfl_xor(ss, off);
        }
        __shared__ float rs[4], rss[4];
        int wid = threadIdx.x >> 6;
        if ((threadIdx.x & 63) == 0){ rs[wid] = s; rss[wid] = ss; }
        __syncthreads();
        if (threadIdx.x == 0){
            stats[bg*16 + part*2]     = rs[0]+rs[1]+rs[2]+rs[3];
            stats[bg*16 + part*2 + 1] = rss[0]+rss[1]+rss[2]+rss[3];
        }
    } else {
        int id = (blockIdx.x - 256)*256 + threadIdx.x;   // 0..8191
        const float* src; uint4* dst; int fi;
        if (id < 6144){ src = qkv_w; dst = Wf; fi = id; }
        else          { src = proj_w; dst = Pf; fi = id - 6144; }
        int l = fi & 63, ks = (fi >> 6) & 7, ob = fi >> 9;
        int o = ob*32 + (l & 31);
        int c = ks*16 + ((l >> 5) << 3);
        const float* s = src + o*128 + c;
        dst[fi] = make_uint4(pack2(s[0],s[1]), pack2(s[2],s[3]), pack2(s[4],s[5]), pack2(s[6],s[7]));
    }
}

// ---------------- K2: MFMA GN+QKV. grid 512 (b = x>>7, tokblk = x&127), block 256 ----------------
__global__ __launch_bounds__(256) void qkv_kernel(const float* __restrict__ x,
                                                  const float* __restrict__ stats,
                                                  const float* __restrict__ gamma,
                                                  const float* __restrict__ beta,
                                                  const uint4* __restrict__ Wf,
                                                  const float* __restrict__ bias,
                                                  uint4* __restrict__ Qf,
                                                  uint4* __restrict__ Kf,
                                                  uint4* __restrict__ Vf){
    __shared__ float gaL[128], beL[128], biasL[384];
    int b = blockIdx.x >> 7, tokblk = blockIdx.x & 127;
    int t = threadIdx.x, lane = t & 63, wv = t >> 6;
    if (t < 128){
        int g = t >> 4;
        float S = 0.f, SS = 0.f;
        #pragma unroll
        for (int p = 0; p < 8; p++){
            S  += stats[(b*8 + g)*16 + p*2];
            SS += stats[(b*8 + g)*16 + p*2 + 1];
        }
        float mean = S * (1.f/65536.f);
        float rstd = rsqrtf(SS * (1.f/65536.f) - mean*mean + 1e-5f);
        float ga = gamma[t] * rstd;
        gaL[t] = ga; beL[t] = beta[t] - mean*ga;
    }
    if (t < 192){ biasL[t] = bias[t]; biasL[t+192] = bias[t+192]; }
    __syncthreads();

    int h = lane >> 5, tl = lane & 31;
    uint4 xf[8];
    const float* xb = x + (size_t)b*128*HW + tokblk*32 + tl;
    #pragma unroll
    for (int ks = 0; ks < 8; ks++){
        int c0 = ks*16 + h*8;
        float4 g0 = *(float4*)&gaL[c0], g1 = *(float4*)&gaL[c0+4];
        float4 e0 = *(float4*)&beL[c0], e1 = *(float4*)&beL[c0+4];
        float v[8];
        #pragma unroll
        for (int j = 0; j < 8; j++) v[j] = xb[(size_t)(c0+j)*HW];
        v[0] = fmaf(v[0], g0.x, e0.x); v[1] = fmaf(v[1], g0.y, e0.y);
        v[2] = fmaf(v[2], g0.z, e0.z); v[3] = fmaf(v[3], g0.w, e0.w);
        v[4] = fmaf(v[4], g1.x, e1.x); v[5] = fmaf(v[5], g1.y, e1.y);
        v[6] = fmaf(v[6], g1.z, e1.z); v[7] = fmaf(v[7], g1.w, e1.w);
        xf[ks] = make_uint4(pack2(v[0],v[1]), pack2(v[2],v[3]), pack2(v[4],v[5]), pack2(v[6],v[7]));
    }

    bool up = (lane >= 32);
    #pragma unroll
    for (int i = 0; i < 3; i++){
        int ob = wv*3 + i;
        uint4 wf[8];
        #pragma unroll
        for (int ks = 0; ks < 8; ks++) wf[ks] = Wf[(ob*8 + ks)*64 + lane];
        f32x16 D;
        #pragma unroll
        for (int r = 0; r < 16; r++) D[r] = 0.f;
        if (ob < 8){
            #pragma unroll
            for (int ks = 0; ks < 8; ks++)
                D = __builtin_amdgcn_mfma_f32_32x32x16_bf16(as_bf8(wf[ks]), as_bf8(xf[ks]), D, 0,0,0);
            #pragma unroll
            for (int r = 0; r < 16; r++)
                D[r] += biasL[ob*32 + (r&3) + 8*(r>>2) + 4*h];
            u32 pk[8], xch[8];
            #pragma unroll
            for (int j = 0; j < 8; j++) pk[j] = pack2(D[2*j], D[2*j+1]);
            #pragma unroll
            for (int j = 0; j < 8; j++) xch[j] = __shfl_xor(pk[j], 32);
            uint4 F0 = up ? make_uint4(xch[2],xch[3],pk[2],pk[3]) : make_uint4(pk[0],pk[1],xch[0],xch[1]);
            uint4 F1 = up ? make_uint4(xch[6],xch[7],pk[6],pk[7]) : make_uint4(pk[4],pk[5],xch[4],xch[5]);
            uint4* dst = (ob < 4) ? Qf : Kf;
            int obl = ob & 3;
            size_t base = (((size_t)b*128 + tokblk)*8 + obl*2)*64 + lane;
            dst[base] = F0; dst[base + 64] = F1;
        } else {
            #pragma unroll
            for (int ks = 0; ks < 8; ks++)
                D = __builtin_amdgcn_mfma_f32_32x32x16_bf16(as_bf8(xf[ks]), as_bf8(wf[ks]), D, 0,0,0);
            int nb = ob - 8;
            float vb = biasL[256 + nb*32 + tl];
            #pragma unroll
            for (int r = 0; r < 16; r++) D[r] += vb;
            u32 pk[8], xch[8];
            #pragma unroll
            for (int j = 0; j < 8; j++) pk[j] = pack2(D[2*j], D[2*j+1]);
            #pragma unroll
            for (int j = 0; j < 8; j++) xch[j] = __shfl_xor(pk[j], 32);
            uint4 F0 = up ? make_uint4(xch[2],xch[3],pk[2],pk[3]) : make_uint4(pk[0],pk[1],xch[0],xch[1]);
            uint4 F1 = up ? make_uint4(xch[6],xch[7],pk[6],pk[7]) : make_uint4(pk[4],pk[5],xch[4],xch[5]);
            int it = tokblk >> 1, t2 = tokblk & 1;
            size_t base = ((((size_t)b*64 + it)*4 + nb)*4 + t2*2)*64 + lane;
            Vf[base] = F0; Vf[base + 64] = F1;
        }
    }
}

// ---------------- K3: MFMA flash attention, single-buffer LDS-staged K/V ----------------
// grid 512 (pair = blockIdx.x&7 -> (b,ksp); qx = blockIdx.x>>3), block 256 = 4 waves (qh,kh).
// The two qh waves fetch IDENTICAL K/V fragments from L2 (2x duplication, ~22 TB/s
// aggregate). Stage the 32KB K+V tile in LDS once per iter. SINGLE buffer + TWO barriers
// per iteration (textbook separation: all tile(it) reads drained before overwrite; all
// writes published before tile(it+1) reads). No LDS aliasing: fsm/lred are separate
// arrays exactly as in the round-6 passing kernel. T14 split retained: global loads for
// tile it+1 issue before compute on tile it, draining after PV. 64.25 KB LDS -> 2 blk/CU.
__global__ __launch_bounds__(256, 2) void attn_kernel(const uint4* __restrict__ Qf,
                                                      const uint4* __restrict__ Kf,
                                                      const uint4* __restrict__ Vf,
                                                      uint4* __restrict__ Opart,
                                                      float* __restrict__ lsum){
    __shared__ uint4 tile[2048];   // 32KB: K tile (1024 u4) + V tile (1024 u4)
    __shared__ float fsm[8192];    // 32KB: kh=1 O hand-off (separate, NO aliasing)
    __shared__ float lred[64];

    int pair = blockIdx.x & 7, qx = blockIdx.x >> 3;
    int b = pair >> 1, ksp = pair & 1;
    int t = threadIdx.x, lane = t & 63, wv = t >> 6;
    int qh = wv >> 1, kh = wv & 1;
    const float SC2 = 0.12751744361402804f;   // (1/sqrt(128))*log2(e)
    const float B2  = -11.541560327111707f;   // -8*log2(e)

    uint4 qf[8];
    const uint4* qptr = Qf + (((size_t)b*128 + qx*2 + qh)*8)*64 + lane;
    #pragma unroll
    for (int ks = 0; ks < 8; ks++) qf[ks] = qptr[ks*64];

    f32x16 O[4];
    #pragma unroll
    for (int nb = 0; nb < 4; nb++)
        #pragma unroll
        for (int r = 0; r < 16; r++) O[nb][r] = 0.f;
    float l_i = 0.f;

    // block-level K/V tile streams (16KB each per iter, contiguous fragment order)
    const uint4* Kbase = Kf + (((size_t)b*128 + ksp*64)*8)*64;
    const uint4* Vbase = Vf + (((size_t)b*64  + ksp*32)*16)*64;

    // per-wave fragment offsets inside the staged tile (== round-2 global offsets)
    const int kofs = kh*512 + lane;          // + ks*64
    const int vofs = 1024 + kh*128 + lane;   // + nb*256 (+64)

    // prologue: stage tile 0 (block covers [0,2048) exactly once)
    #pragma unroll
    for (int i = 0; i < 4; i++) tile[t + i*256]        = Kbase[t + i*256];
    #pragma unroll
    for (int i = 0; i < 4; i++) tile[1024 + t + i*256] = Vbase[t + i*256];
    __syncthreads();

    for (int it = 0; it < 32; it++){
        // 1) issue global loads for tile it+1 (registers; vmcnt drains at step 5)
        uint4 st[8];
        if (it < 31){
            const uint4* kt = Kbase + (it+1)*1024;
            const uint4* vt = Vbase + (it+1)*1024;
            #pragma unroll
            for (int i = 0; i < 4; i++) st[i]   = kt[t + i*256];
            #pragma unroll
            for (int i = 0; i < 4; i++) st[4+i] = vt[t + i*256];
        }

        // 2) operand reads from LDS (contiguous 1KB ds_read_b128, conflict-free)
        uint4 kf[8], vf[8];
        #pragma unroll
        for (int ks = 0; ks < 8; ks++) kf[ks] = tile[kofs + ks*64];
        #pragma unroll
        for (int nb = 0; nb < 4; nb++){
            vf[nb*2]   = tile[vofs + nb*256];
            vf[nb*2+1] = tile[vofs + nb*256 + 64];
        }

        // 3) S' = K·Q^T (this wave's 32 kt): split chain for ILP
        f32x16 Sa, Sb;
        #pragma unroll
        for (int r = 0; r < 16; r++){ Sa[r] = 0.f; Sb[r] = 0.f; }
        #pragma unroll
        for (int ks = 0; ks < 4; ks++)
            Sa = __builtin_amdgcn_mfma_f32_32x32x16_bf16(as_bf8(kf[ks]), as_bf8(qf[ks]), Sa, 0,0,0);
        #pragma unroll
        for (int ks = 4; ks < 8; ks++)
            Sb = __builtin_amdgcn_mfma_f32_32x32x16_bf16(as_bf8(kf[ks]), as_bf8(qf[ks]), Sb, 0,0,0);
        #pragma unroll
        for (int r = 0; r < 16; r++) Sa[r] += Sb[r];

        // softmax: e = 2^(S*SC2 + B2) == exp(S*SC - 8)
        float psum = 0.f;
        u32 pk[8];
        #pragma unroll
        for (int q = 0; q < 4; q++){
            float e0 = exp2_hw(__fmaf_rn(Sa[q*4+0], SC2, B2));
            float e1 = exp2_hw(__fmaf_rn(Sa[q*4+1], SC2, B2));
            float e2 = exp2_hw(__fmaf_rn(Sa[q*4+2], SC2, B2));
            float e3 = exp2_hw(__fmaf_rn(Sa[q*4+3], SC2, B2));
            psum += (e0+e1)+(e2+e3);
            pk[2*q] = cvtpk(e0,e1); pk[2*q+1] = cvtpk(e2,e3);
        }
        {   // l_i += own + partner(lane^32) via one permlane32_swap
            u32 ua = __float_as_uint(psum), ub = ua;
            plswap(ua, ub);
            l_i += __uint_as_float(ua) + __uint_as_float(ub);
        }

        // P fragment exchange across the lane-32 split: 2x2 half-transposes.
        plswap(pk[0], pk[2]); plswap(pk[1], pk[3]);
        plswap(pk[4], pk[6]); plswap(pk[5], pk[7]);
        uint4 fr0 = make_uint4(pk[0], pk[1], pk[2], pk[3]);
        uint4 fr1 = make_uint4(pk[4], pk[5], pk[6], pk[7]);

        // 4) PV, operands swapped: O^T[ch][qr] = V^T · P^T  (A=vf, B=fr)
        #pragma unroll
        for (int nb = 0; nb < 4; nb++){
            O[nb] = __builtin_amdgcn_mfma_f32_32x32x16_bf16(as_bf8(vf[nb*2]),   as_bf8(fr0), O[nb], 0,0,0);
            O[nb] = __builtin_amdgcn_mfma_f32_32x32x16_bf16(as_bf8(vf[nb*2+1]), as_bf8(fr1), O[nb], 0,0,0);
        }

        // 5) barrier: ALL waves' tile(it) reads are drained; then overwrite; then publish
        __syncthreads();
        if (it < 31){
            #pragma unroll
            for (int i = 0; i < 4; i++) tile[t + i*256]        = st[i];
            #pragma unroll
            for (int i = 0; i < 4; i++) tile[1024 + t + i*256] = st[4+i];
        }
        __syncthreads();
    }

    // cross-kh reduce (fsm/lred are dedicated arrays — no aliasing)
    if (kh == 1){
        #pragma unroll
        for (int nb = 0; nb < 4; nb++)
            #pragma unroll
            for (int r = 0; r < 16; r++)
                fsm[((qh*4+nb)*16 + r)*64 + lane] = O[nb][r];
        if (lane < 32) lred[qh*32 + lane] = l_i;
    }
    __syncthreads();
    if (kh == 0){
        float lt = l_i + lred[qh*32 + (lane & 31)];
        if (lane < 32) lsum[((size_t)(ksp*4 + b))*HW + (qx*2+qh)*32 + lane] = lt;
        bool up = (lane >= 32);
        uint4* oc = Opart + (size_t)ksp*262144 + (((size_t)b*128 + qx*2 + qh)*8)*64 + lane;
        #pragma unroll
        for (int nb = 0; nb < 4; nb++){
            #pragma unroll
            for (int r = 0; r < 16; r++) O[nb][r] += fsm[((qh*4+nb)*16 + r)*64 + lane];
            u32 pk[8], xch[8];
            #pragma unroll
            for (int j = 0; j < 8; j++) pk[j] = pack2(O[nb][2*j], O[nb][2*j+1]);
            #pragma unroll
            for (int j = 0; j < 8; j++) xch[j] = __shfl_xor(pk[j], 32);
            uint4 F0 = up ? make_uint4(xch[2],xch[3],pk[2],pk[3]) : make_uint4(pk[0],pk[1],xch[0],xch[1]);
            uint4 F1 = up ? make_uint4(xch[6],xch[7],pk[6],pk[7]) : make_uint4(pk[4],pk[5],xch[4],xch[5]);
            oc[(nb*2)*64]     = F0;
            oc[(nb*2 + 1)*64] = F1;
        }
    }
}

// ---------------- K4: proj, 2-chunk direct MFMA. Op lives in WORKSPACE ----------------
// (round-4/5 NaN root-caused to the Opart-aliases-d_out race; ws placement removes all
// inter-block ordering assumptions.) Direct bf16-chunk MFMA: P·(O0+O1)·diag(inv) =
// (ΣP·Oc)·diag(inv) — combine VALU removed.
__global__ __launch_bounds__(256) void proj2_kernel(const uint4* __restrict__ Op,
                                                    const float* __restrict__ lsum,
                                                    const uint4* __restrict__ Pf,
                                                    const float* __restrict__ bias,
                                                    const float* __restrict__ x,
                                                    float* __restrict__ out){
    __shared__ float biasL[128];
    int t = threadIdx.x, lane = t & 63, wv = t >> 6;
    if (t < 128) biasL[t] = bias[t];
    __syncthreads();
    int b = blockIdx.x >> 6, tk = blockIdx.x & 63;
    int tokb2 = wv & 1, obh = wv >> 1;
    int tokblk = tk*2 + tokb2;
    int h = lane >> 5, tl = lane & 31;

    int rowg = b*HW + tokblk*32 + tl;
    float inv = 1.f / (lsum[rowg] + lsum[16384 + rowg]);
    const uint4* c0p = Op + (((size_t)b*128 + tokblk)*8)*64 + lane;
    uint4 of0[8], of1[8];
    #pragma unroll
    for (int ks = 0; ks < 8; ks++){
        of0[ks] = c0p[ks*64];
        of1[ks] = c0p[262144 + ks*64];
    }

    #pragma unroll
    for (int i = 0; i < 2; i++){
        int ob = obh*2 + i;
        uint4 pf[8];
        #pragma unroll
        for (int ks = 0; ks < 8; ks++) pf[ks] = Pf[(ob*8 + ks)*64 + lane];
        f32x16 D;
        #pragma unroll
        for (int r = 0; r < 16; r++) D[r] = 0.f;
        #pragma unroll
        for (int ks = 0; ks < 8; ks++)
            D = __builtin_amdgcn_mfma_f32_32x32x16_bf16(as_bf8(pf[ks]), as_bf8(of0[ks]), D, 0,0,0);
        #pragma unroll
        for (int ks = 0; ks < 8; ks++)
            D = __builtin_amdgcn_mfma_f32_32x32x16_bf16(as_bf8(pf[ks]), as_bf8(of1[ks]), D, 0,0,0);
        #pragma unroll
        for (int r = 0; r < 16; r++){
            int o = ob*32 + (r&3) + 8*(r>>2) + 4*h;
            size_t gi = ((size_t)b*128 + o)*HW + tokblk*32 + tl;
            out[gi] = x[gi] + biasL[o] + D[r]*inv;
        }
    }
}

extern "C" void kernel_launch(void* const* d_in, const int* in_sizes, int n_in,
                              void* d_out, int out_size, void* d_ws, size_t ws_size,
                              hipStream_t stream){
    const float* x      = (const float*)d_in[0];
    const float* norm_w = (const float*)d_in[1];
    const float* norm_b = (const float*)d_in[2];
    const float* qkv_w  = (const float*)d_in[3];
    const float* qkv_b  = (const float*)d_in[4];
    const float* proj_w = (const float*)d_in[5];
    const float* proj_b = (const float*)d_in[6];
    float* out = (float*)d_out;

    // ws layout (21.24 MB total; round-3 proved ws_size >= 29.75 MB):
    // stats 2K | Qf 4.19M | Kf 4.19M | Vf 4.19M | lsum 128K | Wf 96K | Pf 32K | Op2 8.39M
    char* w = (char*)d_ws;
    float* stats = (float*)w;
    uint4* Qf   = (uint4*)(w + 2048);
    uint4* Kf   = (uint4*)(w + 4196352);
    uint4* Vf   = (uint4*)(w + 8390656);
    float* lsum = (float*)(w + 12584960);
    uint4* Wf   = (uint4*)(w + 12716032);
    uint4* Pf   = (uint4*)(w + 12814336);
    uint4* Op2  = (uint4*)(w + 12847104);

    gnw_kernel<<<288, 256, 0, stream>>>(x, stats, qkv_w, proj_w, Wf, Pf);
    qkv_kernel<<<512, 256, 0, stream>>>(x, stats, norm_w, norm_b, Wf, qkv_b, Qf, Kf, Vf);
    attn_kernel<<<512, 256, 0, stream>>>(Qf, Kf, Vf, Op2, lsum);
    proj2_kernel<<<256, 256, 0, stream>>>(Op2, lsum, Pf, proj_b, x, out);
}

// Round 9
// 132.477 us; speedup vs baseline: 1.7263x; 1.7263x over previous
//
#include <hip/hip_runtime.h>

typedef unsigned short u16;
typedef unsigned int   u32;

#define HW 4096
#define NC 128

typedef __bf16 bf16x8 __attribute__((ext_vector_type(8)));
typedef float  f32x16 __attribute__((ext_vector_type(16)));

__device__ __forceinline__ bf16x8 as_bf8(uint4 u){
    union { uint4 u; bf16x8 b; } c; c.u = u; return c.b;
}
__device__ __forceinline__ u32 pack2(float a, float b){
    return ((__float_as_uint(a) + 0x8000u) >> 16) | ((__float_as_uint(b) + 0x8000u) & 0xffff0000u);
}
__device__ __forceinline__ float bf_lo(u32 u){ return __uint_as_float(u << 16); }
__device__ __forceinline__ float bf_hi(u32 u){ return __uint_as_float(u & 0xffff0000u); }

// 2^x via the HW transcendental unit (avoid glibc __exp2f macro collision)
__device__ __forceinline__ float exp2_hw(float x){ return __builtin_amdgcn_exp2f(x); }

// v_permlane32_swap_b32: 2x2 transpose of 32-lane halves between two VGPRs.
__device__ __forceinline__ void plswap(u32 &a, u32 &b){
    asm("v_permlane32_swap_b32 %0, %1" : "+v"(a), "+v"(b));
}
// proper-RNE pack of two f32 into packed bf16x2 (lo=a, hi=b), 1 instr
__device__ __forceinline__ u32 cvtpk(float a, float b){
    u32 r; asm("v_cvt_pk_bf16_f32 %0, %1, %2" : "=v"(r) : "v"(a), "v"(b)); return r;
}

// L2 -> LDS direct DMA, 16B/lane, no VGPR round-trip. LDS dest must be
// wave-uniform base (+ lane*16 applied by HW); global src is per-lane.
__device__ __forceinline__ void gld_lds16(const uint4* g, uint4* l){
    __builtin_amdgcn_global_load_lds((const __attribute__((address_space(1))) void*)g,
                                     (__attribute__((address_space(3))) void*)l,
                                     16, 0, 0);
}

// ---------------- K1: fused GroupNorm partial sums + weight prep ----------------
__global__ __launch_bounds__(256) void gnw_kernel(const float* __restrict__ x,
                                                  float* __restrict__ stats,
                                                  const float* __restrict__ qkv_w,
                                                  const float* __restrict__ proj_w,
                                                  uint4* __restrict__ Wf,
                                                  uint4* __restrict__ Pf){
    if (blockIdx.x < 256){
        int bg = blockIdx.x >> 3, part = blockIdx.x & 7;
        const float4* p = (const float4*)(x + (size_t)bg * 65536 + part * 8192);
        float s = 0.f, ss = 0.f;
        #pragma unroll
        for (int i = 0; i < 8; i++){
            float4 u = p[threadIdx.x + i*256];
            s  += u.x + u.y + u.z + u.w;
            ss += u.x*u.x + u.y*u.y + u.z*u.z + u.w*u.w;
        }
        #pragma unroll
        for (int off = 32; off > 0; off >>= 1){
            s  += __shfl_xor(s,  off);
            ss += __shfl_xor(ss, off);
        }
        __shared__ float rs[4], rss[4];
        int wid = threadIdx.x >> 6;
        if ((threadIdx.x & 63) == 0){ rs[wid] = s; rss[wid] = ss; }
        __syncthreads();
        if (threadIdx.x == 0){
            stats[bg*16 + part*2]     = rs[0]+rs[1]+rs[2]+rs[3];
            stats[bg*16 + part*2 + 1] = rss[0]+rss[1]+rss[2]+rss[3];
        }
    } else {
        int id = (blockIdx.x - 256)*256 + threadIdx.x;   // 0..8191
        const float* src; uint4* dst; int fi;
        if (id < 6144){ src = qkv_w; dst = Wf; fi = id; }
        else          { src = proj_w; dst = Pf; fi = id - 6144; }
        int l = fi & 63, ks = (fi >> 6) & 7, ob = fi >> 9;
        int o = ob*32 + (l & 31);
        int c = ks*16 + ((l >> 5) << 3);
        const float* s = src + o*128 + c;
        dst[fi] = make_uint4(pack2(s[0],s[1]), pack2(s[2],s[3]), pack2(s[4],s[5]), pack2(s[6],s[7]));
    }
}

// ---------------- K2: MFMA GN+QKV. grid 512 (b = x>>7, tokblk = x&127), block 256 ----------------
__global__ __launch_bounds__(256) void qkv_kernel(const float* __restrict__ x,
                                                  const float* __restrict__ stats,
                                                  const float* __restrict__ gamma,
                                                  const float* __restrict__ beta,
                                                  const uint4* __restrict__ Wf,
                                                  const float* __restrict__ bias,
                                                  uint4* __restrict__ Qf,
                                                  uint4* __restrict__ Kf,
                                                  uint4* __restrict__ Vf){
    __shared__ float gaL[128], beL[128], biasL[384];
    int b = blockIdx.x >> 7, tokblk = blockIdx.x & 127;
    int t = threadIdx.x, lane = t & 63, wv = t >> 6;
    if (t < 128){
        int g = t >> 4;
        float S = 0.f, SS = 0.f;
        #pragma unroll
        for (int p = 0; p < 8; p++){
            S  += stats[(b*8 + g)*16 + p*2];
            SS += stats[(b*8 + g)*16 + p*2 + 1];
        }
        float mean = S * (1.f/65536.f);
        float rstd = rsqrtf(SS * (1.f/65536.f) - mean*mean + 1e-5f);
        float ga = gamma[t] * rstd;
        gaL[t] = ga; beL[t] = beta[t] - mean*ga;
    }
    if (t < 192){ biasL[t] = bias[t]; biasL[t+192] = bias[t+192]; }
    __syncthreads();

    int h = lane >> 5, tl = lane & 31;
    uint4 xf[8];
    const float* xb = x + (size_t)b*128*HW + tokblk*32 + tl;
    #pragma unroll
    for (int ks = 0; ks < 8; ks++){
        int c0 = ks*16 + h*8;
        float4 g0 = *(float4*)&gaL[c0], g1 = *(float4*)&gaL[c0+4];
        float4 e0 = *(float4*)&beL[c0], e1 = *(float4*)&beL[c0+4];
        float v[8];
        #pragma unroll
        for (int j = 0; j < 8; j++) v[j] = xb[(size_t)(c0+j)*HW];
        v[0] = fmaf(v[0], g0.x, e0.x); v[1] = fmaf(v[1], g0.y, e0.y);
        v[2] = fmaf(v[2], g0.z, e0.z); v[3] = fmaf(v[3], g0.w, e0.w);
        v[4] = fmaf(v[4], g1.x, e1.x); v[5] = fmaf(v[5], g1.y, e1.y);
        v[6] = fmaf(v[6], g1.z, e1.z); v[7] = fmaf(v[7], g1.w, e1.w);
        xf[ks] = make_uint4(pack2(v[0],v[1]), pack2(v[2],v[3]), pack2(v[4],v[5]), pack2(v[6],v[7]));
    }

    bool up = (lane >= 32);
    #pragma unroll
    for (int i = 0; i < 3; i++){
        int ob = wv*3 + i;
        uint4 wf[8];
        #pragma unroll
        for (int ks = 0; ks < 8; ks++) wf[ks] = Wf[(ob*8 + ks)*64 + lane];
        f32x16 D;
        #pragma unroll
        for (int r = 0; r < 16; r++) D[r] = 0.f;
        if (ob < 8){
            #pragma unroll
            for (int ks = 0; ks < 8; ks++)
                D = __builtin_amdgcn_mfma_f32_32x32x16_bf16(as_bf8(wf[ks]), as_bf8(xf[ks]), D, 0,0,0);
            #pragma unroll
            for (int r = 0; r < 16; r++)
                D[r] += biasL[ob*32 + (r&3) + 8*(r>>2) + 4*h];
            u32 pk[8], xch[8];
            #pragma unroll
            for (int j = 0; j < 8; j++) pk[j] = pack2(D[2*j], D[2*j+1]);
            #pragma unroll
            for (int j = 0; j < 8; j++) xch[j] = __shfl_xor(pk[j], 32);
            uint4 F0 = up ? make_uint4(xch[2],xch[3],pk[2],pk[3]) : make_uint4(pk[0],pk[1],xch[0],xch[1]);
            uint4 F1 = up ? make_uint4(xch[6],xch[7],pk[6],pk[7]) : make_uint4(pk[4],pk[5],xch[4],xch[5]);
            uint4* dst = (ob < 4) ? Qf : Kf;
            int obl = ob & 3;
            size_t base = (((size_t)b*128 + tokblk)*8 + obl*2)*64 + lane;
            dst[base] = F0; dst[base + 64] = F1;
        } else {
            #pragma unroll
            for (int ks = 0; ks < 8; ks++)
                D = __builtin_amdgcn_mfma_f32_32x32x16_bf16(as_bf8(xf[ks]), as_bf8(wf[ks]), D, 0,0,0);
            int nb = ob - 8;
            float vb = biasL[256 + nb*32 + tl];
            #pragma unroll
            for (int r = 0; r < 16; r++) D[r] += vb;
            u32 pk[8], xch[8];
            #pragma unroll
            for (int j = 0; j < 8; j++) pk[j] = pack2(D[2*j], D[2*j+1]);
            #pragma unroll
            for (int j = 0; j < 8; j++) xch[j] = __shfl_xor(pk[j], 32);
            uint4 F0 = up ? make_uint4(xch[2],xch[3],pk[2],pk[3]) : make_uint4(pk[0],pk[1],xch[0],xch[1]);
            uint4 F1 = up ? make_uint4(xch[6],xch[7],pk[6],pk[7]) : make_uint4(pk[4],pk[5],xch[4],xch[5]);
            int it = tokblk >> 1, t2 = tokblk & 1;
            size_t base = ((((size_t)b*64 + it)*4 + nb)*4 + t2*2)*64 + lane;
            Vf[base] = F0; Vf[base + 64] = F1;
        }
    }
}

// ---------------- K3: MFMA flash attention, global_load_lds-staged K/V ----------------
// grid 512 (pair = blockIdx.x&7 -> (b,ksp); qx = blockIdx.x>>3), block 256 = 4 waves (qh,kh).
// Bottleneck model (r6 counters): 128 L2->VGPR dwordx4 instrs per CU per iter ~= 2048cy
// of vector-memory service vs 1024cy MFMA -> memory-pipe-bound at 60% combined util.
// Fix: stage the 32KB K+V tile ONCE per block via global_load_lds DMA (no VGPRs held ->
// no scratch spill, round-8's failure mode). Double buffer + ONE barrier/iter: DMA writes
// target tile[cur^1], ds_reads target tile[cur] (disjoint); the barrier's implicit
// vmcnt(0)+lgkmcnt(0) drain publishes DMA and retires reads. Wave wv stages 512
// contiguous uint4 (8 DMA instrs, uniform LDS base, per-lane global addr = linear layout
// exactly as global_load_lds requires). Epilogue fsm/lred alias the quiescent tile.
__global__ __launch_bounds__(256, 2) void attn_kernel(const uint4* __restrict__ Qf,
                                                      const uint4* __restrict__ Kf,
                                                      const uint4* __restrict__ Vf,
                                                      uint4* __restrict__ Opart,
                                                      float* __restrict__ lsum){
    __shared__ uint4 tile[2][2048];     // 64KB: per buffer, K (1024 u4) + V (1024 u4)
    float* fsm  = (float*)&tile[0][0];  // 32KB epilogue O hand-off (tile quiescent then)
    float* lred = (float*)&tile[1][0];  // 256B epilogue l hand-off

    int pair = blockIdx.x & 7, qx = blockIdx.x >> 3;
    int b = pair >> 1, ksp = pair & 1;
    int t = threadIdx.x, lane = t & 63, wv = t >> 6;
    int qh = wv >> 1, kh = wv & 1;
    const float SC2 = 0.12751744361402804f;   // (1/sqrt(128))*log2(e)
    const float B2  = -11.541560327111707f;   // -8*log2(e)

    uint4 qf[8];
    const uint4* qptr = Qf + (((size_t)b*128 + qx*2 + qh)*8)*64 + lane;
    #pragma unroll
    for (int ks = 0; ks < 8; ks++) qf[ks] = qptr[ks*64];

    f32x16 O[4];
    #pragma unroll
    for (int nb = 0; nb < 4; nb++)
        #pragma unroll
        for (int r = 0; r < 16; r++) O[nb][r] = 0.f;
    float l_i = 0.f;

    // block-level K/V tile streams (1024 uint4 per iter-slice each)
    const uint4* Kbase = Kf + (((size_t)b*128 + ksp*64)*8)*64;
    const uint4* Vbase = Vf + (((size_t)b*64  + ksp*32)*16)*64;

    // this wave's DMA source base: waves 0,1 stage K; waves 2,3 stage V.
    // tile[j] = (j<1024) ? Kslice[j] : Vslice[j-1024];  j = wv*512 + i*64 + lane
    const uint4* gsb = ((wv < 2) ? Kbase : Vbase) + (wv & 1)*512 + lane;
    const int ldsb = wv*512;   // uniform per wave

    // per-wave fragment offsets inside a staged tile (== round-2 global offsets)
    const int kofs = kh*512 + lane;          // + ks*64
    const int vofs = 1024 + kh*128 + lane;   // + nb*256 (+64)

    // prologue: DMA-stage tile 0, then publish
    #pragma unroll
    for (int i = 0; i < 8; i++) gld_lds16(gsb + i*64, &tile[0][ldsb + i*64]);
    __syncthreads();

    for (int it = 0; it < 32; it++){
        int cur = it & 1;

        // 1) DMA-stage slice it+1 into the other buffer (no registers held)
        if (it < 31){
            const uint4* gs = gsb + (size_t)(it+1)*1024;
            #pragma unroll
            for (int i = 0; i < 8; i++) gld_lds16(gs + i*64, &tile[cur^1][ldsb + i*64]);
        }

        // 2) operand reads from LDS (contiguous 1KB ds_read_b128, conflict-free)
        uint4 kf[8], vf[8];
        #pragma unroll
        for (int ks = 0; ks < 8; ks++) kf[ks] = tile[cur][kofs + ks*64];
        #pragma unroll
        for (int nb = 0; nb < 4; nb++){
            vf[nb*2]   = tile[cur][vofs + nb*256];
            vf[nb*2+1] = tile[cur][vofs + nb*256 + 64];
        }

        // 3) S' = K·Q^T (this wave's 32 kt): split chain for ILP
        f32x16 Sa, Sb;
        #pragma unroll
        for (int r = 0; r < 16; r++){ Sa[r] = 0.f; Sb[r] = 0.f; }
        #pragma unroll
        for (int ks = 0; ks < 4; ks++)
            Sa = __builtin_amdgcn_mfma_f32_32x32x16_bf16(as_bf8(kf[ks]), as_bf8(qf[ks]), Sa, 0,0,0);
        #pragma unroll
        for (int ks = 4; ks < 8; ks++)
            Sb = __builtin_amdgcn_mfma_f32_32x32x16_bf16(as_bf8(kf[ks]), as_bf8(qf[ks]), Sb, 0,0,0);
        #pragma unroll
        for (int r = 0; r < 16; r++) Sa[r] += Sb[r];

        // softmax: e = 2^(S*SC2 + B2) == exp(S*SC - 8)
        float psum = 0.f;
        u32 pk[8];
        #pragma unroll
        for (int q = 0; q < 4; q++){
            float e0 = exp2_hw(__fmaf_rn(Sa[q*4+0], SC2, B2));
            float e1 = exp2_hw(__fmaf_rn(Sa[q*4+1], SC2, B2));
            float e2 = exp2_hw(__fmaf_rn(Sa[q*4+2], SC2, B2));
            float e3 = exp2_hw(__fmaf_rn(Sa[q*4+3], SC2, B2));
            psum += (e0+e1)+(e2+e3);
            pk[2*q] = cvtpk(e0,e1); pk[2*q+1] = cvtpk(e2,e3);
        }
        {   // l_i += own + partner(lane^32) via one permlane32_swap
            u32 ua = __float_as_uint(psum), ub = ua;
            plswap(ua, ub);
            l_i += __uint_as_float(ua) + __uint_as_float(ub);
        }

        // P fragment exchange across the lane-32 split: 2x2 half-transposes.
        plswap(pk[0], pk[2]); plswap(pk[1], pk[3]);
        plswap(pk[4], pk[6]); plswap(pk[5], pk[7]);
        uint4 fr0 = make_uint4(pk[0], pk[1], pk[2], pk[3]);
        uint4 fr1 = make_uint4(pk[4], pk[5], pk[6], pk[7]);

        // 4) PV, operands swapped: O^T[ch][qr] = V^T · P^T  (A=vf, B=fr)
        #pragma unroll
        for (int nb = 0; nb < 4; nb++){
            O[nb] = __builtin_amdgcn_mfma_f32_32x32x16_bf16(as_bf8(vf[nb*2]),   as_bf8(fr0), O[nb], 0,0,0);
            O[nb] = __builtin_amdgcn_mfma_f32_32x32x16_bf16(as_bf8(vf[nb*2+1]), as_bf8(fr1), O[nb], 0,0,0);
        }

        // 5) one barrier: drains this wave's DMA (vmcnt0) + LDS reads; publishes buffer
        __syncthreads();
    }

    // cross-kh reduce (tile quiescent after final barrier; fsm/lred alias it)
    if (kh == 1){
        #pragma unroll
        for (int nb = 0; nb < 4; nb++)
            #pragma unroll
            for (int r = 0; r < 16; r++)
                fsm[((qh*4+nb)*16 + r)*64 + lane] = O[nb][r];
        if (lane < 32) lred[qh*32 + lane] = l_i;
    }
    __syncthreads();
    if (kh == 0){
        float lt = l_i + lred[qh*32 + (lane & 31)];
        if (lane < 32) lsum[((size_t)(ksp*4 + b))*HW + (qx*2+qh)*32 + lane] = lt;
        bool up = (lane >= 32);
        uint4* oc = Opart + (size_t)ksp*262144 + (((size_t)b*128 + qx*2 + qh)*8)*64 + lane;
        #pragma unroll
        for (int nb = 0; nb < 4; nb++){
            #pragma unroll
            for (int r = 0; r < 16; r++) O[nb][r] += fsm[((qh*4+nb)*16 + r)*64 + lane];
            u32 pk[8], xch[8];
            #pragma unroll
            for (int j = 0; j < 8; j++) pk[j] = pack2(O[nb][2*j], O[nb][2*j+1]);
            #pragma unroll
            for (int j = 0; j < 8; j++) xch[j] = __shfl_xor(pk[j], 32);
            uint4 F0 = up ? make_uint4(xch[2],xch[3],pk[2],pk[3]) : make_uint4(pk[0],pk[1],xch[0],xch[1]);
            uint4 F1 = up ? make_uint4(xch[6],xch[7],pk[6],pk[7]) : make_uint4(pk[4],pk[5],xch[4],xch[5]);
            oc[(nb*2)*64]     = F0;
            oc[(nb*2 + 1)*64] = F1;
        }
    }
}

// ---------------- K4: proj, 2-chunk direct MFMA. Op lives in WORKSPACE ----------------
// (round-4/5 NaN root-caused to the Opart-aliases-d_out race; ws placement removes all
// inter-block ordering assumptions.) Direct bf16-chunk MFMA: P·(O0+O1)·diag(inv) =
// (ΣP·Oc)·diag(inv) — combine VALU removed.
__global__ __launch_bounds__(256) void proj2_kernel(const uint4* __restrict__ Op,
                                                    const float* __restrict__ lsum,
                                                    const uint4* __restrict__ Pf,
                                                    const float* __restrict__ bias,
                                                    const float* __restrict__ x,
                                                    float* __restrict__ out){
    __shared__ float biasL[128];
    int t = threadIdx.x, lane = t & 63, wv = t >> 6;
    if (t < 128) biasL[t] = bias[t];
    __syncthreads();
    int b = blockIdx.x >> 6, tk = blockIdx.x & 63;
    int tokb2 = wv & 1, obh = wv >> 1;
    int tokblk = tk*2 + tokb2;
    int h = lane >> 5, tl = lane & 31;

    int rowg = b*HW + tokblk*32 + tl;
    float inv = 1.f / (lsum[rowg] + lsum[16384 + rowg]);
    const uint4* c0p = Op + (((size_t)b*128 + tokblk)*8)*64 + lane;
    uint4 of0[8], of1[8];
    #pragma unroll
    for (int ks = 0; ks < 8; ks++){
        of0[ks] = c0p[ks*64];
        of1[ks] = c0p[262144 + ks*64];
    }

    #pragma unroll
    for (int i = 0; i < 2; i++){
        int ob = obh*2 + i;
        uint4 pf[8];
        #pragma unroll
        for (int ks = 0; ks < 8; ks++) pf[ks] = Pf[(ob*8 + ks)*64 + lane];
        f32x16 D;
        #pragma unroll
        for (int r = 0; r < 16; r++) D[r] = 0.f;
        #pragma unroll
        for (int ks = 0; ks < 8; ks++)
            D = __builtin_amdgcn_mfma_f32_32x32x16_bf16(as_bf8(pf[ks]), as_bf8(of0[ks]), D, 0,0,0);
        #pragma unroll
        for (int ks = 0; ks < 8; ks++)
            D = __builtin_amdgcn_mfma_f32_32x32x16_bf16(as_bf8(pf[ks]), as_bf8(of1[ks]), D, 0,0,0);
        #pragma unroll
        for (int r = 0; r < 16; r++){
            int o = ob*32 + (r&3) + 8*(r>>2) + 4*h;
            size_t gi = ((size_t)b*128 + o)*HW + tokblk*32 + tl;
            out[gi] = x[gi] + biasL[o] + D[r]*inv;
        }
    }
}

extern "C" void kernel_launch(void* const* d_in, const int* in_sizes, int n_in,
                              void* d_out, int out_size, void* d_ws, size_t ws_size,
                              hipStream_t stream){
    const float* x      = (const float*)d_in[0];
    const float* norm_w = (const float*)d_in[1];
    const float* norm_b = (const float*)d_in[2];
    const float* qkv_w  = (const float*)d_in[3];
    const float* qkv_b  = (const float*)d_in[4];
    const float* proj_w = (const float*)d_in[5];
    const float* proj_b = (const float*)d_in[6];
    float* out = (float*)d_out;

    // ws layout (21.24 MB total; round-3 proved ws_size >= 29.75 MB):
    // stats 2K | Qf 4.19M | Kf 4.19M | Vf 4.19M | lsum 128K | Wf 96K | Pf 32K | Op2 8.39M
    char* w = (char*)d_ws;
    float* stats = (float*)w;
    uint4* Qf   = (uint4*)(w + 2048);
    uint4* Kf   = (uint4*)(w + 4196352);
    uint4* Vf   = (uint4*)(w + 8390656);
    float* lsum = (float*)(w + 12584960);
    uint4* Wf   = (uint4*)(w + 12716032);
    uint4* Pf   = (uint4*)(w + 12814336);
    uint4* Op2  = (uint4*)(w + 12847104);

    gnw_kernel<<<288, 256, 0, stream>>>(x, stats, qkv_w, proj_w, Wf, Pf);
    qkv_kernel<<<512, 256, 0, stream>>>(x, stats, norm_w, norm_b, Wf, qkv_b, Qf, Kf, Vf);
    attn_kernel<<<512, 256, 0, stream>>>(Qf, Kf, Vf, Op2, lsum);
    proj2_kernel<<<256, 256, 0, stream>>>(Op2, lsum, Pf, proj_b, x, out);
}

// Round 10
// 127.706 us; speedup vs baseline: 1.7908x; 1.0374x over previous
//
#include <hip/hip_runtime.h>

typedef unsigned short u16;
typedef unsigned int   u32;

#define HW 4096
#define NC 128

typedef __bf16 bf16x8 __attribute__((ext_vector_type(8)));
typedef float  f32x16 __attribute__((ext_vector_type(16)));

__device__ __forceinline__ bf16x8 as_bf8(uint4 u){
    union { uint4 u; bf16x8 b; } c; c.u = u; return c.b;
}
__device__ __forceinline__ u32 pack2(float a, float b){
    return ((__float_as_uint(a) + 0x8000u) >> 16) | ((__float_as_uint(b) + 0x8000u) & 0xffff0000u);
}
__device__ __forceinline__ float bf_lo(u32 u){ return __uint_as_float(u << 16); }
__device__ __forceinline__ float bf_hi(u32 u){ return __uint_as_float(u & 0xffff0000u); }

// 2^x via the HW transcendental unit (avoid glibc __exp2f macro collision)
__device__ __forceinline__ float exp2_hw(float x){ return __builtin_amdgcn_exp2f(x); }

// v_permlane32_swap_b32: 2x2 transpose of 32-lane halves between two VGPRs.
__device__ __forceinline__ void plswap(u32 &a, u32 &b){
    asm("v_permlane32_swap_b32 %0, %1" : "+v"(a), "+v"(b));
}
// proper-RNE pack of two f32 into packed bf16x2 (lo=a, hi=b), 1 instr
__device__ __forceinline__ u32 cvtpk(float a, float b){
    u32 r; asm("v_cvt_pk_bf16_f32 %0, %1, %2" : "=v"(r) : "v"(a), "v"(b)); return r;
}

// ---------------- K1: fused GroupNorm partial sums + weight prep ----------------
__global__ __launch_bounds__(256) void gnw_kernel(const float* __restrict__ x,
                                                  float* __restrict__ stats,
                                                  const float* __restrict__ qkv_w,
                                                  const float* __restrict__ proj_w,
                                                  uint4* __restrict__ Wf,
                                                  uint4* __restrict__ Pf){
    if (blockIdx.x < 256){
        int bg = blockIdx.x >> 3, part = blockIdx.x & 7;
        const float4* p = (const float4*)(x + (size_t)bg * 65536 + part * 8192);
        float s = 0.f, ss = 0.f;
        #pragma unroll
        for (int i = 0; i < 8; i++){
            float4 u = p[threadIdx.x + i*256];
            s  += u.x + u.y + u.z + u.w;
            ss += u.x*u.x + u.y*u.y + u.z*u.z + u.w*u.w;
        }
        #pragma unroll
        for (int off = 32; off > 0; off >>= 1){
            s  += __shfl_xor(s,  off);
            ss += __shfl_xor(ss, off);
        }
        __shared__ float rs[4], rss[4];
        int wid = threadIdx.x >> 6;
        if ((threadIdx.x & 63) == 0){ rs[wid] = s; rss[wid] = ss; }
        __syncthreads();
        if (threadIdx.x == 0){
            stats[bg*16 + part*2]     = rs[0]+rs[1]+rs[2]+rs[3];
            stats[bg*16 + part*2 + 1] = rss[0]+rss[1]+rss[2]+rss[3];
        }
    } else {
        int id = (blockIdx.x - 256)*256 + threadIdx.x;   // 0..8191
        const float* src; uint4* dst; int fi;
        if (id < 6144){ src = qkv_w; dst = Wf; fi = id; }
        else          { src = proj_w; dst = Pf; fi = id - 6144; }
        int l = fi & 63, ks = (fi >> 6) & 7, ob = fi >> 9;
        int o = ob*32 + (l & 31);
        int c = ks*16 + ((l >> 5) << 3);
        const float* s = src + o*128 + c;
        dst[fi] = make_uint4(pack2(s[0],s[1]), pack2(s[2],s[3]), pack2(s[4],s[5]), pack2(s[6],s[7]));
    }
}

// ---------------- K2: MFMA GN+QKV. grid 512 (b = x>>7, tokblk = x&127), block 256 ----------------
__global__ __launch_bounds__(256) void qkv_kernel(const float* __restrict__ x,
                                                  const float* __restrict__ stats,
                                                  const float* __restrict__ gamma,
                                                  const float* __restrict__ beta,
                                                  const uint4* __restrict__ Wf,
                                                  const float* __restrict__ bias,
                                                  uint4* __restrict__ Qf,
                                                  uint4* __restrict__ Kf,
                                                  uint4* __restrict__ Vf){
    __shared__ float gaL[128], beL[128], biasL[384];
    int b = blockIdx.x >> 7, tokblk = blockIdx.x & 127;
    int t = threadIdx.x, lane = t & 63, wv = t >> 6;
    if (t < 128){
        int g = t >> 4;
        float S = 0.f, SS = 0.f;
        #pragma unroll
        for (int p = 0; p < 8; p++){
            S  += stats[(b*8 + g)*16 + p*2];
            SS += stats[(b*8 + g)*16 + p*2 + 1];
        }
        float mean = S * (1.f/65536.f);
        float rstd = rsqrtf(SS * (1.f/65536.f) - mean*mean + 1e-5f);
        float ga = gamma[t] * rstd;
        gaL[t] = ga; beL[t] = beta[t] - mean*ga;
    }
    if (t < 192){ biasL[t] = bias[t]; biasL[t+192] = bias[t+192]; }
    __syncthreads();

    int h = lane >> 5, tl = lane & 31;
    uint4 xf[8];
    const float* xb = x + (size_t)b*128*HW + tokblk*32 + tl;
    #pragma unroll
    for (int ks = 0; ks < 8; ks++){
        int c0 = ks*16 + h*8;
        float4 g0 = *(float4*)&gaL[c0], g1 = *(float4*)&gaL[c0+4];
        float4 e0 = *(float4*)&beL[c0], e1 = *(float4*)&beL[c0+4];
        float v[8];
        #pragma unroll
        for (int j = 0; j < 8; j++) v[j] = xb[(size_t)(c0+j)*HW];
        v[0] = fmaf(v[0], g0.x, e0.x); v[1] = fmaf(v[1], g0.y, e0.y);
        v[2] = fmaf(v[2], g0.z, e0.z); v[3] = fmaf(v[3], g0.w, e0.w);
        v[4] = fmaf(v[4], g1.x, e1.x); v[5] = fmaf(v[5], g1.y, e1.y);
        v[6] = fmaf(v[6], g1.z, e1.z); v[7] = fmaf(v[7], g1.w, e1.w);
        xf[ks] = make_uint4(pack2(v[0],v[1]), pack2(v[2],v[3]), pack2(v[4],v[5]), pack2(v[6],v[7]));
    }

    bool up = (lane >= 32);
    #pragma unroll
    for (int i = 0; i < 3; i++){
        int ob = wv*3 + i;
        uint4 wf[8];
        #pragma unroll
        for (int ks = 0; ks < 8; ks++) wf[ks] = Wf[(ob*8 + ks)*64 + lane];
        f32x16 D;
        #pragma unroll
        for (int r = 0; r < 16; r++) D[r] = 0.f;
        if (ob < 8){
            #pragma unroll
            for (int ks = 0; ks < 8; ks++)
                D = __builtin_amdgcn_mfma_f32_32x32x16_bf16(as_bf8(wf[ks]), as_bf8(xf[ks]), D, 0,0,0);
            #pragma unroll
            for (int r = 0; r < 16; r++)
                D[r] += biasL[ob*32 + (r&3) + 8*(r>>2) + 4*h];
            u32 pk[8], xch[8];
            #pragma unroll
            for (int j = 0; j < 8; j++) pk[j] = pack2(D[2*j], D[2*j+1]);
            #pragma unroll
            for (int j = 0; j < 8; j++) xch[j] = __shfl_xor(pk[j], 32);
            uint4 F0 = up ? make_uint4(xch[2],xch[3],pk[2],pk[3]) : make_uint4(pk[0],pk[1],xch[0],xch[1]);
            uint4 F1 = up ? make_uint4(xch[6],xch[7],pk[6],pk[7]) : make_uint4(pk[4],pk[5],xch[4],xch[5]);
            uint4* dst = (ob < 4) ? Qf : Kf;
            int obl = ob & 3;
            size_t base = (((size_t)b*128 + tokblk)*8 + obl*2)*64 + lane;
            dst[base] = F0; dst[base + 64] = F1;
        } else {
            #pragma unroll
            for (int ks = 0; ks < 8; ks++)
                D = __builtin_amdgcn_mfma_f32_32x32x16_bf16(as_bf8(xf[ks]), as_bf8(wf[ks]), D, 0,0,0);
            int nb = ob - 8;
            float vb = biasL[256 + nb*32 + tl];
            #pragma unroll
            for (int r = 0; r < 16; r++) D[r] += vb;
            u32 pk[8], xch[8];
            #pragma unroll
            for (int j = 0; j < 8; j++) pk[j] = pack2(D[2*j], D[2*j+1]);
            #pragma unroll
            for (int j = 0; j < 8; j++) xch[j] = __shfl_xor(pk[j], 32);
            uint4 F0 = up ? make_uint4(xch[2],xch[3],pk[2],pk[3]) : make_uint4(pk[0],pk[1],xch[0],xch[1]);
            uint4 F1 = up ? make_uint4(xch[6],xch[7],pk[6],pk[7]) : make_uint4(pk[4],pk[5],xch[4],xch[5]);
            int it = tokblk >> 1, t2 = tokblk & 1;
            size_t base = ((((size_t)b*64 + it)*4 + nb)*4 + t2*2)*64 + lane;
            Vf[base] = F0; Vf[base + 64] = F1;
        }
    }
}

// ---------------- K3: MFMA flash attention, barrier-free K-loop (round-2 exact) ----------------
// grid 512 (pair = blockIdx.x&7 -> (b,ksp); qx = blockIdx.x>>3), block 256 = 4 waves (qh,kh).
// Direct per-wave fragment loads. Staging experiments (reg: r8 spill; DMA: r9 49.4us)
// both failed to beat this — attn is dependency-limited at 2 waves/SIMD, not L2-limited.
__global__ __launch_bounds__(256, 2) void attn_kernel(const uint4* __restrict__ Qf,
                                                      const uint4* __restrict__ Kf,
                                                      const uint4* __restrict__ Vf,
                                                      uint4* __restrict__ Opart,
                                                      float* __restrict__ lsum){
    __shared__ float fsm[8192];    // 32 KB: kh=1 O hand-off
    __shared__ float lred[64];
    int pair = blockIdx.x & 7, qx = blockIdx.x >> 3;
    int b = pair >> 1, ksp = pair & 1;
    int t = threadIdx.x, lane = t & 63, wv = t >> 6;
    int qh = wv >> 1, kh = wv & 1;
    const float SC2 = 0.12751744361402804f;   // (1/sqrt(128))*log2(e)
    const float B2  = -11.541560327111707f;   // -8*log2(e)

    uint4 qf[8];
    const uint4* qptr = Qf + (((size_t)b*128 + qx*2 + qh)*8)*64 + lane;
    #pragma unroll
    for (int ks = 0; ks < 8; ks++) qf[ks] = qptr[ks*64];

    f32x16 O[4];
    #pragma unroll
    for (int nb = 0; nb < 4; nb++)
        #pragma unroll
        for (int r = 0; r < 16; r++) O[nb][r] = 0.f;
    float l_i = 0.f;

    // per-wave fragment streams
    const uint4* kgw = Kf + (((size_t)b*128 + ksp*64)*8)*64 + (kh<<9) + lane;
    const uint4* vgw = Vf + (((size_t)b*64  + ksp*32)*16)*64 + (kh<<7) + lane;

    uint4 kf[8], vf[8];
    #pragma unroll
    for (int ks = 0; ks < 8; ks++) kf[ks] = kgw[ks*64];
    #pragma unroll
    for (int nb = 0; nb < 4; nb++){
        vf[nb*2]   = vgw[nb*256];
        vf[nb*2+1] = vgw[nb*256 + 64];
    }

    for (int it = 0; it < 32; it++){
        // S' = K·Q^T (this wave's 32 kt): split chain for ILP
        f32x16 Sa, Sb;
        #pragma unroll
        for (int r = 0; r < 16; r++){ Sa[r] = 0.f; Sb[r] = 0.f; }
        #pragma unroll
        for (int ks = 0; ks < 4; ks++)
            Sa = __builtin_amdgcn_mfma_f32_32x32x16_bf16(as_bf8(kf[ks]), as_bf8(qf[ks]), Sa, 0,0,0);
        #pragma unroll
        for (int ks = 4; ks < 8; ks++)
            Sb = __builtin_amdgcn_mfma_f32_32x32x16_bf16(as_bf8(kf[ks]), as_bf8(qf[ks]), Sb, 0,0,0);
        #pragma unroll
        for (int r = 0; r < 16; r++) Sa[r] += Sb[r];

        // prefetch next K frags (regs free after the chains above)
        if (it < 31){
            const uint4* kn = kgw + (it+1)*1024;
            #pragma unroll
            for (int ks = 0; ks < 8; ks++) kf[ks] = kn[ks*64];
        }

        // softmax: e = 2^(S*SC2 + B2) == exp(S*SC - 8)
        float psum = 0.f;
        u32 pk[8];
        #pragma unroll
        for (int q = 0; q < 4; q++){
            float e0 = exp2_hw(__fmaf_rn(Sa[q*4+0], SC2, B2));
            float e1 = exp2_hw(__fmaf_rn(Sa[q*4+1], SC2, B2));
            float e2 = exp2_hw(__fmaf_rn(Sa[q*4+2], SC2, B2));
            float e3 = exp2_hw(__fmaf_rn(Sa[q*4+3], SC2, B2));
            psum += (e0+e1)+(e2+e3);
            pk[2*q] = cvtpk(e0,e1); pk[2*q+1] = cvtpk(e2,e3);
        }
        {   // l_i += own + partner(lane^32) via one permlane32_swap
            u32 ua = __float_as_uint(psum), ub = ua;
            plswap(ua, ub);
            l_i += __uint_as_float(ua) + __uint_as_float(ub);
        }

        // P fragment exchange across the lane-32 split: 2x2 half-transposes.
        plswap(pk[0], pk[2]); plswap(pk[1], pk[3]);
        plswap(pk[4], pk[6]); plswap(pk[5], pk[7]);
        uint4 fr0 = make_uint4(pk[0], pk[1], pk[2], pk[3]);
        uint4 fr1 = make_uint4(pk[4], pk[5], pk[6], pk[7]);

        // PV, operands swapped: O^T[ch][qr] = V^T · P^T  (A=vf, B=fr)
        #pragma unroll
        for (int nb = 0; nb < 4; nb++){
            O[nb] = __builtin_amdgcn_mfma_f32_32x32x16_bf16(as_bf8(vf[nb*2]),   as_bf8(fr0), O[nb], 0,0,0);
            O[nb] = __builtin_amdgcn_mfma_f32_32x32x16_bf16(as_bf8(vf[nb*2+1]), as_bf8(fr1), O[nb], 0,0,0);
        }

        // prefetch next V frags
        if (it < 31){
            const uint4* vn = vgw + (it+1)*1024;
            #pragma unroll
            for (int nb = 0; nb < 4; nb++){
                vf[nb*2]   = vn[nb*256];
                vf[nb*2+1] = vn[nb*256 + 64];
            }
        }
    }

    // cross-kh reduce
    if (kh == 1){
        #pragma unroll
        for (int nb = 0; nb < 4; nb++)
            #pragma unroll
            for (int r = 0; r < 16; r++)
                fsm[((qh*4+nb)*16 + r)*64 + lane] = O[nb][r];
        if (lane < 32) lred[qh*32 + lane] = l_i;
    }
    __syncthreads();
    if (kh == 0){
        float lt = l_i + lred[qh*32 + (lane & 31)];
        if (lane < 32) lsum[((size_t)(ksp*4 + b))*HW + (qx*2+qh)*32 + lane] = lt;
        bool up = (lane >= 32);
        uint4* oc = Opart + (size_t)ksp*262144 + (((size_t)b*128 + qx*2 + qh)*8)*64 + lane;
        #pragma unroll
        for (int nb = 0; nb < 4; nb++){
            #pragma unroll
            for (int r = 0; r < 16; r++) O[nb][r] += fsm[((qh*4+nb)*16 + r)*64 + lane];
            u32 pk[8], xch[8];
            #pragma unroll
            for (int j = 0; j < 8; j++) pk[j] = pack2(O[nb][2*j], O[nb][2*j+1]);
            #pragma unroll
            for (int j = 0; j < 8; j++) xch[j] = __shfl_xor(pk[j], 32);
            uint4 F0 = up ? make_uint4(xch[2],xch[3],pk[2],pk[3]) : make_uint4(pk[0],pk[1],xch[0],xch[1]);
            uint4 F1 = up ? make_uint4(xch[6],xch[7],pk[6],pk[7]) : make_uint4(pk[4],pk[5],xch[4],xch[5]);
            oc[(nb*2)*64]     = F0;
            oc[(nb*2 + 1)*64] = F1;
        }
    }
}

// ---------------- K4: proj, grid 512 (1 tokblk/block, 4 waves = 4 ob), LDS-staged Op --------
// Old grid 256 ran 1 block/CU = 1 wave/SIMD (zero latency hiding) with 2x-redundant Op
// loads. Now: 2 blocks/CU; the 16KB Op chunk pair (of0|of1, both contiguous 8KB slices)
// is cooperatively staged in LDS once per block, then each wave MFMAs its own output
// block ob = wv. Direct bf16-chunk MFMA: out = (P·O0 + P·O1)·diag(inv) + bias + x.
__global__ __launch_bounds__(256) void proj_kernel(const uint4* __restrict__ Op,
                                                   const float* __restrict__ lsum,
                                                   const uint4* __restrict__ Pf,
                                                   const float* __restrict__ bias,
                                                   const float* __restrict__ x,
                                                   float* __restrict__ out){
    __shared__ uint4 ofL[1024];    // 16KB: of0 [0,512) | of1 [512,1024)
    __shared__ float biasL[128];
    int t = threadIdx.x, lane = t & 63, ob = t >> 6;
    int b = blockIdx.x >> 7, tokblk = blockIdx.x & 127;
    int h = lane >> 5, tl = lane & 31;

    // stage Op chunks (contiguous 8KB each) + bias
    {
        size_t base0 = ((size_t)b*128 + tokblk)*512;   // of0 slice
        #pragma unroll
        for (int i = 0; i < 2; i++) ofL[i*256 + t]       = Op[base0 + i*256 + t];
        #pragma unroll
        for (int i = 0; i < 2; i++) ofL[512 + i*256 + t] = Op[262144 + base0 + i*256 + t];
    }
    if (t < 128) biasL[t] = bias[t];

    // per-row softmax denominators (both ksp halves)
    int rowg = b*HW + tokblk*32 + tl;
    float inv = 1.f / (lsum[rowg] + lsum[16384 + rowg]);

    // this wave's P-weight fragments (ob = wv)
    uint4 pf[8];
    #pragma unroll
    for (int ks = 0; ks < 8; ks++) pf[ks] = Pf[(ob*8 + ks)*64 + lane];

    __syncthreads();

    f32x16 D;
    #pragma unroll
    for (int r = 0; r < 16; r++) D[r] = 0.f;
    #pragma unroll
    for (int ks = 0; ks < 8; ks++)
        D = __builtin_amdgcn_mfma_f32_32x32x16_bf16(as_bf8(pf[ks]), as_bf8(ofL[ks*64 + lane]), D, 0,0,0);
    #pragma unroll
    for (int ks = 0; ks < 8; ks++)
        D = __builtin_amdgcn_mfma_f32_32x32x16_bf16(as_bf8(pf[ks]), as_bf8(ofL[512 + ks*64 + lane]), D, 0,0,0);

    #pragma unroll
    for (int r = 0; r < 16; r++){
        int o = ob*32 + (r&3) + 8*(r>>2) + 4*h;
        size_t gi = ((size_t)b*128 + o)*HW + tokblk*32 + tl;
        out[gi] = x[gi] + biasL[o] + D[r]*inv;
    }
}

extern "C" void kernel_launch(void* const* d_in, const int* in_sizes, int n_in,
                              void* d_out, int out_size, void* d_ws, size_t ws_size,
                              hipStream_t stream){
    const float* x      = (const float*)d_in[0];
    const float* norm_w = (const float*)d_in[1];
    const float* norm_b = (const float*)d_in[2];
    const float* qkv_w  = (const float*)d_in[3];
    const float* qkv_b  = (const float*)d_in[4];
    const float* proj_w = (const float*)d_in[5];
    const float* proj_b = (const float*)d_in[6];
    float* out = (float*)d_out;

    // ws layout (21.24 MB total; round-3 proved ws_size >= 29.75 MB):
    // stats 2K | Qf 4.19M | Kf 4.19M | Vf 4.19M | lsum 128K | Wf 96K | Pf 32K | Op2 8.39M
    char* w = (char*)d_ws;
    float* stats = (float*)w;
    uint4* Qf   = (uint4*)(w + 2048);
    uint4* Kf   = (uint4*)(w + 4196352);
    uint4* Vf   = (uint4*)(w + 8390656);
    float* lsum = (float*)(w + 12584960);
    uint4* Wf   = (uint4*)(w + 12716032);
    uint4* Pf   = (uint4*)(w + 12814336);
    uint4* Op2  = (uint4*)(w + 12847104);

    gnw_kernel<<<288, 256, 0, stream>>>(x, stats, qkv_w, proj_w, Wf, Pf);
    qkv_kernel<<<512, 256, 0, stream>>>(x, stats, norm_w, norm_b, Wf, qkv_b, Qf, Kf, Vf);
    attn_kernel<<<512, 256, 0, stream>>>(Qf, Kf, Vf, Op2, lsum);
    proj_kernel<<<512, 256, 0, stream>>>(Op2, lsum, Pf, proj_b, x, out);
}